// Round 2
// baseline (445.250 us; speedup 1.0000x reference)
//
#include <hip/hip_runtime.h>
#include <stdint.h>

// Problem shape (fixed by reference): x[4,2048,4096] f32, CB[4096,4096] i8-as-i32, SCB[4096] f32
static constexpr int Mtot = 8192;   // B*S
static constexpr int Ntot = 4096;   // OUT
static constexpr int Ktot = 4096;   // IN

using i32x4  = __attribute__((ext_vector_type(4)))  int;
using i32x16 = __attribute__((ext_vector_type(16))) int;

#define GLD16(gptr, lptr)                                                                   \
  __builtin_amdgcn_global_load_lds((const __attribute__((address_space(1))) void*)(gptr),   \
                                   (__attribute__((address_space(3))) void*)(lptr), 16, 0, 0)

// ---------------------------------------------------------------------------
// Kernel 1: repack CB from harness int32 to int8 (16 MB in ws).
// ---------------------------------------------------------------------------
__global__ __launch_bounds__(256) void pack_cb_kernel(const int* __restrict__ src,
                                                      int8_t* __restrict__ dst) {
  const int idx = blockIdx.x * 256 + threadIdx.x;  // one int4 -> one packed int
  const int4 v = reinterpret_cast<const int4*>(src)[idx];
  const unsigned packed = (unsigned)(v.x & 0xff) | ((unsigned)(v.y & 0xff) << 8) |
                          ((unsigned)(v.z & 0xff) << 16) | ((unsigned)(v.w & 0xff) << 24);
  reinterpret_cast<unsigned*>(dst)[idx] = packed;
}

// ---------------------------------------------------------------------------
// Kernel 2: row-wise dynamic int8 quant of x. One block per row (K=4096).
// ---------------------------------------------------------------------------
__global__ __launch_bounds__(256) void quant_x_kernel(const float* __restrict__ x,
                                                      int8_t* __restrict__ xq,
                                                      float* __restrict__ sx) {
  const int row = blockIdx.x;
  const float4* xr = reinterpret_cast<const float4*>(x + (size_t)row * Ktot);
  float4 v[4];
  float am = 0.f;
#pragma unroll
  for (int i = 0; i < 4; ++i) {
    v[i] = xr[threadIdx.x + i * 256];
    am = fmaxf(am, fmaxf(fmaxf(fabsf(v[i].x), fabsf(v[i].y)),
                         fmaxf(fabsf(v[i].z), fabsf(v[i].w))));
  }
#pragma unroll
  for (int off = 32; off > 0; off >>= 1) am = fmaxf(am, __shfl_xor(am, off));
  __shared__ float wmax[4];
  if ((threadIdx.x & 63) == 0) wmax[threadIdx.x >> 6] = am;
  __syncthreads();
  am = fmaxf(fmaxf(wmax[0], wmax[1]), fmaxf(wmax[2], wmax[3]));
  const float inv = 127.0f / am;
  if (threadIdx.x == 0) sx[row] = am * (1.0f / 127.0f);
  unsigned* dq = reinterpret_cast<unsigned*>(xq + (size_t)row * Ktot);
#pragma unroll
  for (int i = 0; i < 4; ++i) {
    const int q0 = (int)rintf(v[i].x * inv);
    const int q1 = (int)rintf(v[i].y * inv);
    const int q2 = (int)rintf(v[i].z * inv);
    const int q3 = (int)rintf(v[i].w * inv);
    dq[threadIdx.x + i * 256] = (unsigned)(q0 & 0xff) | ((unsigned)(q1 & 0xff) << 8) |
                                ((unsigned)(q2 & 0xff) << 16) | ((unsigned)(q3 & 0xff) << 24);
  }
}

// ---------------------------------------------------------------------------
// Kernel 3: int8 GEMM. 128x128 tile, BK=64, 4 waves, each wave 64x64 via 2x2
// grid of mfma_i32_32x32x32_i8.
//
// LDS layout: row r (0..127) occupies bytes [r*64, r*64+64); the 16-B chunk
// at position p holds global k-chunk (p ^ ((r>>1)&3))  — XOR swizzle.
//   * staging: 4 adjacent lanes fetch the 4 chunks of one row (same 64-B
//     global segment, permuted) -> coalescing unchanged; LDS dst = tid*16
//     (global_load_lds requires wave-uniform base + lane*16).
//   * fragment read of 16 same-parity rows at one chunk position spreads
//     across 4 distinct bank groups -> 2-way max (free per m136), vs the
//     previous 8-way (2.94x) that produced SQ_LDS_BANK_CONFLICT=1.7e7.
// ---------------------------------------------------------------------------
__global__ __launch_bounds__(256) void gemm_i8_kernel(const int8_t* __restrict__ A,
                                                      const int8_t* __restrict__ B,
                                                      const float* __restrict__ sx,
                                                      const float* __restrict__ scb,
                                                      float* __restrict__ C) {
  constexpr int BK = 64;
  __shared__ int8_t As[128 * BK];  // 8 KB
  __shared__ int8_t Bs[128 * BK];  // 8 KB

  const int tid = threadIdx.x;
  const int lane = tid & 63;
  const int wid = tid >> 6;
  const int m0 = blockIdx.y * 128;
  const int n0 = blockIdx.x * 128;
  const int wm = (wid >> 1) * 64;  // wave's 64x64 sub-tile
  const int wn = (wid & 1) * 64;

  // staging: tid -> row (tid>>2), LDS chunk position p = tid&3, global chunk
  // q = p ^ ((row>>1)&3). Row+64 has the same swizzle (64>>1 = 32 ≡ 0 mod 4).
  const int srow = tid >> 2;
  const int scol = (((tid & 3) ^ ((srow >> 1) & 3)) << 4);
  const int8_t* Ag0 = A + (size_t)(m0 + srow) * Ktot + scol;
  const int8_t* Ag1 = A + (size_t)(m0 + 64 + srow) * Ktot + scol;
  const int8_t* Bg0 = B + (size_t)(n0 + srow) * Ktot + scol;
  const int8_t* Bg1 = B + (size_t)(n0 + 64 + srow) * Ktot + scol;
  int8_t* lA0 = &As[tid * 16];
  int8_t* lA1 = &As[4096 + tid * 16];
  int8_t* lB0 = &Bs[tid * 16];
  int8_t* lB1 = &Bs[4096 + tid * 16];

  i32x16 acc[2][2];
#pragma unroll
  for (int i = 0; i < 2; ++i)
#pragma unroll
    for (int j = 0; j < 2; ++j) acc[i][j] = (i32x16)0;

  // A/B fragment for mfma_i32_32x32x32_i8: lane holds row (lane&31),
  // k-bytes [(lane>>5)*16, +16) of the 32-B k-step — byte-pattern analog of
  // the verified 16x16 layout. Chunk index within the 64-B row for k-step s:
  // c = s*2 + (lane>>5); swizzled position = c ^ ((r>>1)&3).
  const int mr = lane & 31;
  const int kh = lane >> 5;
  int offA[2][2], offB[2][2];  // [tile i or j][k-step s] -> LDS byte offset
#pragma unroll
  for (int i = 0; i < 2; ++i) {
    const int r = wm + i * 32 + mr;
    const int sw = (r >> 1) & 3;
#pragma unroll
    for (int s = 0; s < 2; ++s) offA[i][s] = r * 64 + ((((s << 1) + kh) ^ sw) << 4);
  }
#pragma unroll
  for (int j = 0; j < 2; ++j) {
    const int r = wn + j * 32 + mr;
    const int sw = (r >> 1) & 3;
#pragma unroll
    for (int s = 0; s < 2; ++s) offB[j][s] = r * 64 + ((((s << 1) + kh) ^ sw) << 4);
  }

  for (int kt = 0; kt < Ktot; kt += BK) {
    GLD16(Ag0 + kt, lA0);
    GLD16(Ag1 + kt, lA1);
    GLD16(Bg0 + kt, lB0);
    GLD16(Bg1 + kt, lB1);
    __syncthreads();

#pragma unroll
    for (int s = 0; s < 2; ++s) {
      const i32x4 a0 = *reinterpret_cast<const i32x4*>(&As[offA[0][s]]);
      const i32x4 a1 = *reinterpret_cast<const i32x4*>(&As[offA[1][s]]);
      const i32x4 b0 = *reinterpret_cast<const i32x4*>(&Bs[offB[0][s]]);
      const i32x4 b1 = *reinterpret_cast<const i32x4*>(&Bs[offB[1][s]]);
      acc[0][0] = __builtin_amdgcn_mfma_i32_32x32x32_i8(a0, b0, acc[0][0], 0, 0, 0);
      acc[0][1] = __builtin_amdgcn_mfma_i32_32x32x32_i8(a0, b1, acc[0][1], 0, 0, 0);
      acc[1][0] = __builtin_amdgcn_mfma_i32_32x32x32_i8(a1, b0, acc[1][0], 0, 0, 0);
      acc[1][1] = __builtin_amdgcn_mfma_i32_32x32x32_i8(a1, b1, acc[1][1], 0, 0, 0);
    }
    __syncthreads();
  }

  // Epilogue. 32x32 C/D layout (HW-verified, dtype-independent):
  // col = lane&31, row = (reg&3) + 8*(reg>>2) + 4*(lane>>5).
  const int col = lane & 31;
  const int rq = (lane >> 5) << 2;
#pragma unroll
  for (int i = 0; i < 2; ++i) {
    const int gmb = m0 + wm + i * 32;
    float sm[16];
#pragma unroll
    for (int reg = 0; reg < 16; ++reg)
      sm[reg] = sx[gmb + (reg & 3) + ((reg >> 2) << 3) + rq];
#pragma unroll
    for (int j = 0; j < 2; ++j) {
      const int gn = n0 + wn + j * 32 + col;
      const float snv = scb[gn] * (1.0f / 127.0f);
#pragma unroll
      for (int reg = 0; reg < 16; ++reg) {
        const int gm = gmb + (reg & 3) + ((reg >> 2) << 3) + rq;
        C[(size_t)gm * Ntot + gn] = (float)acc[i][j][reg] * sm[reg] * snv;
      }
    }
  }
}

// ---------------------------------------------------------------------------
extern "C" void kernel_launch(void* const* d_in, const int* in_sizes, int n_in,
                              void* d_out, int out_size, void* d_ws, size_t ws_size,
                              hipStream_t stream) {
  const float* x = (const float*)d_in[0];
  const int* CB32 = (const int*)d_in[1];   // harness: integer inputs -> const int*
  const float* SCB = (const float*)d_in[2];
  float* out = (float*)d_out;

  // ws layout: xq (32 MB) | cb8 (16 MB) | sx (32 KB)
  int8_t* xq = (int8_t*)d_ws;
  int8_t* cb8 = (int8_t*)d_ws + (size_t)Mtot * Ktot;
  float* sx = (float*)((int8_t*)d_ws + (size_t)Mtot * Ktot + (size_t)Ntot * Ktot);

  pack_cb_kernel<<<(Ntot * Ktot / 4) / 256, 256, 0, stream>>>(CB32, cb8);
  quant_x_kernel<<<Mtot, 256, 0, stream>>>(x, xq, sx);
  dim3 grid(Ntot / 128, Mtot / 128);  // (32, 64)
  gemm_i8_kernel<<<grid, 256, 0, stream>>>(xq, cb8, sx, SCB, out);
}

// Round 3
// 442.504 us; speedup vs baseline: 1.0062x; 1.0062x over previous
//
#include <hip/hip_runtime.h>
#include <stdint.h>

// Problem shape (fixed by reference): x[4,2048,4096] f32, CB[4096,4096] i8-as-i32, SCB[4096] f32
static constexpr int Mtot = 8192;   // B*S
static constexpr int Ntot = 4096;   // OUT
static constexpr int Ktot = 4096;   // IN

using i32x4 = __attribute__((ext_vector_type(4))) int;

#define GLD16(gptr, lptr)                                                                   \
  __builtin_amdgcn_global_load_lds((const __attribute__((address_space(1))) void*)(gptr),   \
                                   (__attribute__((address_space(3))) void*)(lptr), 16, 0, 0)

// ---------------------------------------------------------------------------
// Kernel 1: repack CB from harness int32 to int8 (16 MB in ws).
// ---------------------------------------------------------------------------
__global__ __launch_bounds__(256) void pack_cb_kernel(const int* __restrict__ src,
                                                      int8_t* __restrict__ dst) {
  const int idx = blockIdx.x * 256 + threadIdx.x;  // one int4 -> one packed int
  const int4 v = reinterpret_cast<const int4*>(src)[idx];
  const unsigned packed = (unsigned)(v.x & 0xff) | ((unsigned)(v.y & 0xff) << 8) |
                          ((unsigned)(v.z & 0xff) << 16) | ((unsigned)(v.w & 0xff) << 24);
  reinterpret_cast<unsigned*>(dst)[idx] = packed;
}

// ---------------------------------------------------------------------------
// Kernel 2: row-wise dynamic int8 quant of x. One block per row (K=4096).
// rint == round-half-even, matching jnp.round.
// ---------------------------------------------------------------------------
__global__ __launch_bounds__(256) void quant_x_kernel(const float* __restrict__ x,
                                                      int8_t* __restrict__ xq,
                                                      float* __restrict__ sx) {
  const int row = blockIdx.x;
  const float4* xr = reinterpret_cast<const float4*>(x + (size_t)row * Ktot);
  float4 v[4];
  float am = 0.f;
#pragma unroll
  for (int i = 0; i < 4; ++i) {
    v[i] = xr[threadIdx.x + i * 256];
    am = fmaxf(am, fmaxf(fmaxf(fabsf(v[i].x), fabsf(v[i].y)),
                         fmaxf(fabsf(v[i].z), fabsf(v[i].w))));
  }
#pragma unroll
  for (int off = 32; off > 0; off >>= 1) am = fmaxf(am, __shfl_xor(am, off));
  __shared__ float wmax[4];
  if ((threadIdx.x & 63) == 0) wmax[threadIdx.x >> 6] = am;
  __syncthreads();
  am = fmaxf(fmaxf(wmax[0], wmax[1]), fmaxf(wmax[2], wmax[3]));
  const float inv = 127.0f / am;
  if (threadIdx.x == 0) sx[row] = am * (1.0f / 127.0f);
  unsigned* dq = reinterpret_cast<unsigned*>(xq + (size_t)row * Ktot);
#pragma unroll
  for (int i = 0; i < 4; ++i) {
    const int q0 = (int)rintf(v[i].x * inv);
    const int q1 = (int)rintf(v[i].y * inv);
    const int q2 = (int)rintf(v[i].z * inv);
    const int q3 = (int)rintf(v[i].w * inv);
    dq[threadIdx.x + i * 256] = (unsigned)(q0 & 0xff) | ((unsigned)(q1 & 0xff) << 8) |
                                ((unsigned)(q2 & 0xff) << 16) | ((unsigned)(q3 & 0xff) << 24);
  }
}

// ---------------------------------------------------------------------------
// Kernel 3: int8 GEMM, m97-mirror structure.
// A = xq [M,K] K-contig, B = CB [N,K] K-contig.
// 128x128 tile, BK=128 BYTES (m97's bytes/iter), 256 threads = 4 waves, each
// wave 64x64 via 4x4 grid of mfma_i32_16x16x64_i8. Per wave per iter:
// 8 GLD16 + 16 ds_read_b128 + 32 MFMA between one barrier pair — byte-exact
// mirror of the verified 874 TF bf16 ladder point. Fused dequant epilogue.
// ---------------------------------------------------------------------------
__global__ __launch_bounds__(256) void gemm_i8_kernel(const int8_t* __restrict__ A,
                                                      const int8_t* __restrict__ B,
                                                      const float* __restrict__ sx,
                                                      const float* __restrict__ scb,
                                                      float* __restrict__ C) {
  constexpr int BK = 128;          // bytes of K per iteration
  __shared__ int8_t As[128 * BK];  // 16 KB, [row][k] row-major
  __shared__ int8_t Bs[128 * BK];  // 16 KB

  const int tid = threadIdx.x;
  const int lane = tid & 63;
  const int wid = tid >> 6;
  const int m0 = blockIdx.y * 128;
  const int n0 = blockIdx.x * 128;
  const int wm = (wid >> 1) * 64;  // wave's 64x64 sub-tile
  const int wn = (wid & 1) * 64;

  // staging: per matrix 16 KB/iter = 4 GLD16/thread. Linear LDS fill:
  // issue i, thread t -> LDS offset i*4096 + t*16 (wave-contiguous, as
  // global_load_lds requires); global row = t>>3 (+32 per issue),
  // col-chunk = (t&7)*16.
  const int srow = tid >> 3;          // 0..31
  const int scol = (tid & 7) * 16;    // 0..112
  const int8_t* Ag[4];
  const int8_t* Bg[4];
#pragma unroll
  for (int i = 0; i < 4; ++i) {
    Ag[i] = A + (size_t)(m0 + srow + 32 * i) * Ktot + scol;
    Bg[i] = B + (size_t)(n0 + srow + 32 * i) * Ktot + scol;
  }

  i32x4 acc[4][4];
#pragma unroll
  for (int i = 0; i < 4; ++i)
#pragma unroll
    for (int j = 0; j < 4; ++j) acc[i][j] = (i32x4)0;

  // A/B fragment for mfma_i32_16x16x64_i8: row = lane&15, k-bytes
  // [(lane>>4)*16, +16) within the 64-B k-slab; slab s at byte offset s*64.
  const int mrow = lane & 15;
  const int kq = (lane >> 4) * 16;

  for (int kt = 0; kt < Ktot; kt += BK) {
#pragma unroll
    for (int i = 0; i < 4; ++i) {
      GLD16(Ag[i] + kt, &As[i * 4096 + tid * 16]);
      GLD16(Bg[i] + kt, &Bs[i * 4096 + tid * 16]);
    }
    __syncthreads();

#pragma unroll
    for (int s = 0; s < 2; ++s) {
      i32x4 af[4], bf[4];
#pragma unroll
      for (int i = 0; i < 4; ++i)
        af[i] = *reinterpret_cast<const i32x4*>(&As[(wm + i * 16 + mrow) * BK + s * 64 + kq]);
#pragma unroll
      for (int j = 0; j < 4; ++j)
        bf[j] = *reinterpret_cast<const i32x4*>(&Bs[(wn + j * 16 + mrow) * BK + s * 64 + kq]);
#pragma unroll
      for (int i = 0; i < 4; ++i)
#pragma unroll
        for (int j = 0; j < 4; ++j)
          acc[i][j] = __builtin_amdgcn_mfma_i32_16x16x64_i8(af[i], bf[j], acc[i][j], 0, 0, 0);
    }
    __syncthreads();
  }

  // Epilogue: C/D layout col=lane&15, row=(lane>>4)*4+reg (HW-verified,
  // dtype-independent). y = acc * sx[m] * (SCB[n]/127).
  const int col = lane & 15;
  const int rbase = (lane >> 4) * 4;
#pragma unroll
  for (int i = 0; i < 4; ++i) {
    const int gmb = m0 + wm + i * 16 + rbase;
    float sm[4];
#pragma unroll
    for (int r = 0; r < 4; ++r) sm[r] = sx[gmb + r];
#pragma unroll
    for (int j = 0; j < 4; ++j) {
      const int gn = n0 + wn + j * 16 + col;
      const float snv = scb[gn] * (1.0f / 127.0f);
#pragma unroll
      for (int r = 0; r < 4; ++r)
        C[(size_t)(gmb + r) * Ntot + gn] = (float)acc[i][j][r] * sm[r] * snv;
    }
  }
}

// ---------------------------------------------------------------------------
extern "C" void kernel_launch(void* const* d_in, const int* in_sizes, int n_in,
                              void* d_out, int out_size, void* d_ws, size_t ws_size,
                              hipStream_t stream) {
  const float* x = (const float*)d_in[0];
  const int* CB32 = (const int*)d_in[1];   // harness: integer inputs -> const int*
  const float* SCB = (const float*)d_in[2];
  float* out = (float*)d_out;

  // ws layout: xq (32 MB) | cb8 (16 MB) | sx (32 KB)
  int8_t* xq = (int8_t*)d_ws;
  int8_t* cb8 = (int8_t*)d_ws + (size_t)Mtot * Ktot;
  float* sx = (float*)((int8_t*)d_ws + (size_t)Mtot * Ktot + (size_t)Ntot * Ktot);

  pack_cb_kernel<<<(Ntot * Ktot / 4) / 256, 256, 0, stream>>>(CB32, cb8);
  quant_x_kernel<<<Mtot, 256, 0, stream>>>(x, xq, sx);
  dim3 grid(Ntot / 128, Mtot / 128);  // (32, 64)
  gemm_i8_kernel<<<grid, 256, 0, stream>>>(xq, cb8, sx, SCB, out);
}